// Round 4
// baseline (224.071 us; speedup 1.0000x reference)
//
#include <hip/hip_runtime.h>

typedef unsigned long long ull;
typedef float f4 __attribute__((ext_vector_type(4)));

#define TOKENS 2048
#define KNN    32
#define VOCAB  32000

// per-lane re-test + sorted-descending 8-slot insert (u64 key = valbits<<32|idx)
#define INS1(val, idx) do {                                                  \
    unsigned u_ = __float_as_uint(val);                                      \
    if (u_ > thr_) {                                                         \
        ull k_ = (((ull)u_) << 32) | (unsigned)(idx);                        \
        if (k_ > t7) {                                                       \
            ull tmp_;                                                        \
            if (k_ > t0) { tmp_ = t0; t0 = k_; k_ = tmp_; }                  \
            if (k_ > t1) { tmp_ = t1; t1 = k_; k_ = tmp_; }                  \
            if (k_ > t2) { tmp_ = t2; t2 = k_; k_ = tmp_; }                  \
            if (k_ > t3) { tmp_ = t3; t3 = k_; k_ = tmp_; }                  \
            if (k_ > t4) { tmp_ = t4; t4 = k_; k_ = tmp_; }                  \
            if (k_ > t5) { tmp_ = t5; t5 = k_; k_ = tmp_; }                  \
            if (k_ > t6) { tmp_ = t6; t6 = k_; k_ = tmp_; }                  \
            t7 = (k_ > t7) ? k_ : t7;                                        \
        }                                                                    \
    }                                                                        \
} while (0)

// process one float4: zero-store, max4 pretest vs shared threshold, rare insert
#define PROC(i) do {                                                         \
    f4 v_ = np4[(i)];                                                        \
    o4[(i)] = z4;                                                            \
    float m_ = fmaxf(fmaxf(v_.x, v_.y), fmaxf(v_.z, v_.w));                  \
    unsigned thr_ = s_thr;                                                   \
    if (__float_as_uint(m_) > thr_) {                                        \
        INS1(v_.x, 4 * (i) + 0);                                             \
        INS1(v_.y, 4 * (i) + 1);                                             \
        INS1(v_.z, 4 * (i) + 2);                                             \
        INS1(v_.w, 4 * (i) + 3);                                             \
        unsigned h7_ = (unsigned)(t7 >> 32);                                 \
        if (h7_ > thr_) atomicMax(&s_thr, h7_);                              \
    }                                                                        \
} while (0)

__global__ __launch_bounds__(256, 6)
void rc_kernel(const int*   __restrict__ tgt_index,
               const float* __restrict__ knn_dists,
               const float* __restrict__ knn_key,
               const float* __restrict__ net_probs,
               const float* __restrict__ net_sel,
               const float* __restrict__ W_func, const float* __restrict__ b_func,
               const float* __restrict__ W1a,    const float* __restrict__ b1a,
               const float* __restrict__ W1b,    const float* __restrict__ b1b,
               const float* __restrict__ W2a,    const float* __restrict__ b2a,
               const float* __restrict__ W2b,    const float* __restrict__ b2b,
               float* __restrict__ out)
{
    const int t   = blockIdx.x;
    const int tid = threadIdx.x;

    __shared__ int      s_tgt[KNN];
    __shared__ float    s_dist[KNN];
    __shared__ float    s_cnt[KNN];
    __shared__ float    s_top8[8];
    __shared__ ull      s_wmax[4];
    __shared__ unsigned s_thr;

    if (tid == 0) s_thr = 0u;

    // ---- per-k loads (lanes 0..31) ----
    int   tg = 0;
    float d = 0.f, lk = 0.f, ls = 0.f;
    if (tid < KNN) {
        tg = tgt_index[t * KNN + tid];
        d  = knn_dists[t * KNN + tid];
        lk = logf(knn_key[t * KNN + tid]);
        ls = logf(net_sel[t * KNN + tid]);
        s_tgt[tid]  = tg;
        s_dist[tid] = d;
    }
    __syncthreads();   // s_thr initialized before anyone reads it

    // ---- Phase 1: stream network_probs (top-8 scan) + zero the output row ----
    ull t0 = 0, t1 = 0, t2 = 0, t3 = 0, t4 = 0, t5 = 0, t6 = 0, t7 = 0;
    const f4* np4 = (const f4*)(net_probs + (size_t)t * VOCAB);
    f4*       o4  = (f4*)(out + (size_t)t * VOCAB);
    const f4  z4  = (f4){0.f, 0.f, 0.f, 0.f};
    // 8000 float4s per row: 31 uniform iterations + tail for tid<64
    #pragma unroll 2
    for (int k = 0; k < 31; ++k) {
        int i = tid + (k << 8);
        PROC(i);
    }
    if (tid < 64) {
        int i = tid + (31 << 8);
        PROC(i);
    }
    __syncthreads();

    // ---- Phase 2: extract global top-8 (8 rounds of max-extraction) ----
    for (int r = 0; r < 8; ++r) {
        ull c = t0;                       // thread's current best (list sorted desc)
        #pragma unroll
        for (int off = 1; off < 64; off <<= 1) {
            ull o = __shfl_xor(c, off);
            if (o > c) c = o;
        }
        if ((tid & 63) == 0) s_wmax[tid >> 6] = c;
        __syncthreads();
        ull g = s_wmax[0];
        if (s_wmax[1] > g) g = s_wmax[1];
        if (s_wmax[2] > g) g = s_wmax[2];
        if (s_wmax[3] > g) g = s_wmax[3];
        if (t0 == g && g != 0ULL) {       // unique owner pops its head
            t0 = t1; t1 = t2; t2 = t3; t3 = t4; t4 = t5; t5 = t6; t6 = t7; t7 = 0;
        }
        if (tid == 0) s_top8[r] = __uint_as_float((unsigned)(g >> 32));
        __syncthreads();
    }

    // ---- Phase 3a: label counts (distinct, reference never counts label 0) ----
    if (tid < KNN) {
        int fo = (tg != 0) ? 1 : 0;
        if (fo) {
            for (int j = 0; j < tid; ++j)
                if (s_tgt[j] == tg) { fo = 0; break; }
        }
        int c = fo;
        #pragma unroll
        for (int off = 1; off < KNN; off <<= 1) {
            int n = __shfl_up(c, off, KNN);
            if (tid >= off) c += n;
        }
        s_cnt[tid] = (float)c;
    }
    __syncthreads();

    // ---- Phase 3b: tiny MLPs, softmaxes, scatter ----
    if (tid < KNN) {
        // noise_logit: Linear(2,4) -> tanh -> Linear(4,1)
        float noise = b1b[0];
        #pragma unroll
        for (int j = 0; j < 4; ++j) {
            float z = tanhf(W1a[2 * j] * lk + W1a[2 * j + 1] * ls + b1a[j]);
            noise += W1b[j] * z;
        }

        // sim_lambda = W_func . [log(top8) | log_key | log_sel] + b_func
        float sp = W_func[8 + tid] * lk + W_func[40 + tid] * ls;
        if (tid < 8) sp += W_func[tid] * logf(s_top8[tid]);
        #pragma unroll
        for (int off = 16; off; off >>= 1) sp += __shfl_xor(sp, off, KNN);
        float sim = sp + b_func[0];

        // lambda_logit: Linear(64,32) -> tanh -> Linear(32,2); lane = hidden unit
        float h = b2a[tid];
        const float* wr = W2a + tid * 64;
        #pragma unroll 8
        for (int i = 0; i < KNN; ++i) h += wr[i] * s_dist[i];
        #pragma unroll 8
        for (int i = 0; i < KNN; ++i) h += wr[KNN + i] * s_cnt[i];
        h = tanhf(h);
        float p0 = W2b[tid] * h;
        float p1 = W2b[KNN + tid] * h;
        #pragma unroll
        for (int off = 16; off; off >>= 1) {
            p0 += __shfl_xor(p0, off, KNN);
            p1 += __shfl_xor(p1, off, KNN);
        }
        float l0 = p0 + b2b[0];
        float l1 = p1 + b2b[1];

        float tempe = 1.f / (1.f + expf(-l1));          // sigmoid(l1)
        float lam   = 1.f / (1.f + expf(-(l0 - sim)));  // softmax([l0,sim])[0]

        // probs = softmax(-d*tempe + noise) over K
        float logit = -d * tempe + noise;
        float mx = logit;
        #pragma unroll
        for (int off = 16; off; off >>= 1) mx = fmaxf(mx, __shfl_xor(mx, off, KNN));
        float e = expf(logit - mx);
        float se = e;
        #pragma unroll
        for (int off = 16; off; off >>= 1) se += __shfl_xor(se, off, KNN);
        float p = e / se;

        // scatter, last-occurrence-wins on duplicate indices (numpy semantics)
        bool wrte = true;
        for (int j = tid + 1; j < KNN; ++j)
            if (s_tgt[j] == tg) { wrte = false; break; }
        if (wrte) out[(size_t)t * VOCAB + tg] = p;

        if (tid == 0) out[(size_t)TOKENS * VOCAB + t] = lam;
    }
}

extern "C" void kernel_launch(void* const* d_in, const int* in_sizes, int n_in,
                              void* d_out, int out_size, void* d_ws, size_t ws_size,
                              hipStream_t stream) {
    rc_kernel<<<TOKENS, 256, 0, stream>>>(
        (const int*)  d_in[0],   // tgt_index
        (const float*)d_in[1],   // knn_dists
        (const float*)d_in[2],   // knn_key_feature
        (const float*)d_in[3],   // network_probs
        (const float*)d_in[4],   // network_select_probs
        (const float*)d_in[5],  (const float*)d_in[6],   // W_func, b_func
        (const float*)d_in[7],  (const float*)d_in[8],   // W1a, b1a
        (const float*)d_in[9],  (const float*)d_in[10],  // W1b, b1b
        (const float*)d_in[11], (const float*)d_in[12],  // W2a, b2a
        (const float*)d_in[13], (const float*)d_in[14],  // W2b, b2b
        (float*)d_out);
}

// Round 5
// 174.102 us; speedup vs baseline: 1.2870x; 1.2870x over previous
//
#include <hip/hip_runtime.h>

typedef unsigned long long ull;
typedef float f4 __attribute__((ext_vector_type(4)));

#define TOKENS 2048
#define KNN    32
#define VOCAB  32000

// per-lane 32-bit register threshold pretest + rare u64 sorted-insert
#define INS1(val, idx) do {                                                  \
    unsigned u_ = __float_as_uint(val);                                      \
    if (u_ > thr) {                                                          \
        ull k_ = (((ull)u_) << 32) | (unsigned)(idx);                        \
        if (k_ > t7) {                                                       \
            ull tmp_;                                                        \
            if (k_ > t0) { tmp_ = t0; t0 = k_; k_ = tmp_; }                  \
            if (k_ > t1) { tmp_ = t1; t1 = k_; k_ = tmp_; }                  \
            if (k_ > t2) { tmp_ = t2; t2 = k_; k_ = tmp_; }                  \
            if (k_ > t3) { tmp_ = t3; t3 = k_; k_ = tmp_; }                  \
            if (k_ > t4) { tmp_ = t4; t4 = k_; k_ = tmp_; }                  \
            if (k_ > t5) { tmp_ = t5; t5 = k_; k_ = tmp_; }                  \
            if (k_ > t6) { tmp_ = t6; t6 = k_; k_ = tmp_; }                  \
            t7 = (k_ > t7) ? k_ : t7;                                        \
            thr = (unsigned)(t7 >> 32);                                      \
        }                                                                    \
    }                                                                        \
} while (0)

// one float4: max4 pretest vs register threshold; register-only slow path
#define PROC(i) do {                                                         \
    f4 v_ = np4[(i)];                                                        \
    float m_ = fmaxf(fmaxf(v_.x, v_.y), fmaxf(v_.z, v_.w));                  \
    if (__float_as_uint(m_) > thr) {                                         \
        INS1(v_.x, 4 * (i) + 0);                                             \
        INS1(v_.y, 4 * (i) + 1);                                             \
        INS1(v_.z, 4 * (i) + 2);                                             \
        INS1(v_.w, 4 * (i) + 3);                                             \
    }                                                                        \
} while (0)

__global__ __launch_bounds__(256, 8)
void rc_kernel(const int*   __restrict__ tgt_index,
               const float* __restrict__ knn_dists,
               const float* __restrict__ knn_key,
               const float* __restrict__ net_probs,
               const float* __restrict__ net_sel,
               const float* __restrict__ W_func, const float* __restrict__ b_func,
               const float* __restrict__ W1a,    const float* __restrict__ b1a,
               const float* __restrict__ W1b,    const float* __restrict__ b1b,
               const float* __restrict__ W2a,    const float* __restrict__ b2a,
               const float* __restrict__ W2b,    const float* __restrict__ b2b,
               float* __restrict__ out)
{
    const int t   = blockIdx.x;
    const int tid = threadIdx.x;

    __shared__ int   s_tgt[KNN];
    __shared__ float s_dist[KNN];
    __shared__ float s_cnt[KNN];
    __shared__ float s_top8[8];
    __shared__ ull   s_wmax[4];

    // ---- per-k loads (lanes 0..31) ----
    int   tg = 0;
    float d = 0.f, lk = 0.f, ls = 0.f;
    if (tid < KNN) {
        tg = tgt_index[t * KNN + tid];
        d  = knn_dists[t * KNN + tid];
        lk = logf(knn_key[t * KNN + tid]);
        ls = logf(net_sel[t * KNN + tid]);
        s_tgt[tid]  = tg;
        s_dist[tid] = d;
    }

    // ---- Phase 1: read-only top-8 scan of network_probs ----
    ull t0 = 0, t1 = 0, t2 = 0, t3 = 0, t4 = 0, t5 = 0, t6 = 0, t7 = 0;
    unsigned thr = 0;
    const f4* np4 = (const f4*)(net_probs + (size_t)t * VOCAB);
    // 8000 float4s per row: 31 uniform iterations + tail for tid<64
    #pragma unroll 4
    for (int k = 0; k < 31; ++k) {
        PROC(tid + (k << 8));
    }
    if (tid < 64) {
        PROC(tid + (31 << 8));
    }
    __syncthreads();

    // ---- Phase 2: extract global top-8 (8 rounds of max-extraction) ----
    for (int r = 0; r < 8; ++r) {
        ull c = t0;                       // thread's current best (list sorted desc)
        #pragma unroll
        for (int off = 1; off < 64; off <<= 1) {
            ull o = __shfl_xor(c, off);
            if (o > c) c = o;
        }
        if ((tid & 63) == 0) s_wmax[tid >> 6] = c;
        __syncthreads();
        ull g = s_wmax[0];
        if (s_wmax[1] > g) g = s_wmax[1];
        if (s_wmax[2] > g) g = s_wmax[2];
        if (s_wmax[3] > g) g = s_wmax[3];
        if (t0 == g && g != 0ULL) {       // unique owner pops its head
            t0 = t1; t1 = t2; t2 = t3; t3 = t4; t4 = t5; t5 = t6; t6 = t7; t7 = 0;
        }
        if (tid == 0) s_top8[r] = __uint_as_float((unsigned)(g >> 32));
        __syncthreads();
    }

    // ---- Phase 3a: label counts (distinct, reference never counts label 0) ----
    if (tid < KNN) {
        int fo = (tg != 0) ? 1 : 0;
        if (fo) {
            for (int j = 0; j < tid; ++j)
                if (s_tgt[j] == tg) { fo = 0; break; }
        }
        int c = fo;
        #pragma unroll
        for (int off = 1; off < KNN; off <<= 1) {
            int n = __shfl_up(c, off, KNN);
            if (tid >= off) c += n;
        }
        s_cnt[tid] = (float)c;
    }
    __syncthreads();

    // ---- Phase 3b: tiny MLPs, softmaxes, scatter ----
    if (tid < KNN) {
        // noise_logit: Linear(2,4) -> tanh -> Linear(4,1)
        float noise = b1b[0];
        #pragma unroll
        for (int j = 0; j < 4; ++j) {
            float z = tanhf(W1a[2 * j] * lk + W1a[2 * j + 1] * ls + b1a[j]);
            noise += W1b[j] * z;
        }

        // sim_lambda = W_func . [log(top8) | log_key | log_sel] + b_func
        float sp = W_func[8 + tid] * lk + W_func[40 + tid] * ls;
        if (tid < 8) sp += W_func[tid] * logf(s_top8[tid]);
        #pragma unroll
        for (int off = 16; off; off >>= 1) sp += __shfl_xor(sp, off, KNN);
        float sim = sp + b_func[0];

        // lambda_logit: Linear(64,32) -> tanh -> Linear(32,2); lane = hidden unit
        float h = b2a[tid];
        const float* wr = W2a + tid * 64;
        #pragma unroll 8
        for (int i = 0; i < KNN; ++i) h += wr[i] * s_dist[i];
        #pragma unroll 8
        for (int i = 0; i < KNN; ++i) h += wr[KNN + i] * s_cnt[i];
        h = tanhf(h);
        float p0 = W2b[tid] * h;
        float p1 = W2b[KNN + tid] * h;
        #pragma unroll
        for (int off = 16; off; off >>= 1) {
            p0 += __shfl_xor(p0, off, KNN);
            p1 += __shfl_xor(p1, off, KNN);
        }
        float l0 = p0 + b2b[0];
        float l1 = p1 + b2b[1];

        float tempe = 1.f / (1.f + expf(-l1));          // sigmoid(l1)
        float lam   = 1.f / (1.f + expf(-(l0 - sim)));  // softmax([l0,sim])[0]

        // probs = softmax(-d*tempe + noise) over K
        float logit = -d * tempe + noise;
        float mx = logit;
        #pragma unroll
        for (int off = 16; off; off >>= 1) mx = fmaxf(mx, __shfl_xor(mx, off, KNN));
        float e = expf(logit - mx);
        float se = e;
        #pragma unroll
        for (int off = 16; off; off >>= 1) se += __shfl_xor(se, off, KNN);
        float p = e / se;

        // scatter, last-occurrence-wins on duplicate indices (numpy semantics)
        bool wrte = true;
        for (int j = tid + 1; j < KNN; ++j)
            if (s_tgt[j] == tg) { wrte = false; break; }
        if (wrte) out[(size_t)t * VOCAB + tg] = p;

        if (tid == 0) out[(size_t)TOKENS * VOCAB + t] = lam;
    }
}

extern "C" void kernel_launch(void* const* d_in, const int* in_sizes, int n_in,
                              void* d_out, int out_size, void* d_ws, size_t ws_size,
                              hipStream_t stream) {
    // zero-fill the whole output (knn_prob + lambda region) at pure-write BW
    hipMemsetAsync(d_out, 0, (size_t)out_size * sizeof(float), stream);
    // then compute top-8 / MLPs and scatter the 32 probs + lambda per token
    rc_kernel<<<TOKENS, 256, 0, stream>>>(
        (const int*)  d_in[0],   // tgt_index
        (const float*)d_in[1],   // knn_dists
        (const float*)d_in[2],   // knn_key_feature
        (const float*)d_in[3],   // network_probs
        (const float*)d_in[4],   // network_select_probs
        (const float*)d_in[5],  (const float*)d_in[6],   // W_func, b_func
        (const float*)d_in[7],  (const float*)d_in[8],   // W1a, b1a
        (const float*)d_in[9],  (const float*)d_in[10],  // W1b, b1b
        (const float*)d_in[11], (const float*)d_in[12],  // W2a, b2a
        (const float*)d_in[13], (const float*)d_in[14],  // W2b, b2b
        (float*)d_out);
}

// Round 6
// 138.363 us; speedup vs baseline: 1.6194x; 1.2583x over previous
//
#include <hip/hip_runtime.h>

typedef unsigned long long ull;
typedef float f4 __attribute__((ext_vector_type(4)));

#define TOKENS 2048
#define KNN    32
#define VOCAB  32000

// branch-free sorted-descending 8-float insert (values only, 16 ops), guarded
#define INSF(vv) do {                                                        \
    float x_ = (vv);                                                         \
    if (x_ > t7) {                                                           \
        float h_;                                                            \
        h_ = fmaxf(t0, x_); x_ = fminf(t0, x_); t0 = h_;                     \
        h_ = fmaxf(t1, x_); x_ = fminf(t1, x_); t1 = h_;                     \
        h_ = fmaxf(t2, x_); x_ = fminf(t2, x_); t2 = h_;                     \
        h_ = fmaxf(t3, x_); x_ = fminf(t3, x_); t3 = h_;                     \
        h_ = fmaxf(t4, x_); x_ = fminf(t4, x_); t4 = h_;                     \
        h_ = fmaxf(t5, x_); x_ = fminf(t5, x_); t5 = h_;                     \
        h_ = fmaxf(t6, x_); x_ = fminf(t6, x_); t6 = h_;                     \
        t7 = fmaxf(t7, x_);                                                  \
    }                                                                        \
} while (0)

// one float4: fused zero-store + max4 pretest + cheap f32 inserts
#define PROC(i) do {                                                         \
    f4 v_ = np4[(i)];                                                        \
    o4[(i)] = z4;                                                            \
    float m_ = fmaxf(fmaxf(v_.x, v_.y), fmaxf(v_.z, v_.w));                  \
    if (m_ > t7) {                                                           \
        INSF(v_.x); INSF(v_.y); INSF(v_.z); INSF(v_.w);                      \
    }                                                                        \
} while (0)

// u64 sorted insert for the (cold) phase-2 merge
#define INSK(key) do {                                                       \
    ull k_ = (key);                                                          \
    if (k_ > c7) {                                                           \
        ull tmp_;                                                            \
        if (k_ > c0) { tmp_ = c0; c0 = k_; k_ = tmp_; }                      \
        if (k_ > c1) { tmp_ = c1; c1 = k_; k_ = tmp_; }                      \
        if (k_ > c2) { tmp_ = c2; c2 = k_; k_ = tmp_; }                      \
        if (k_ > c3) { tmp_ = c3; c3 = k_; k_ = tmp_; }                      \
        if (k_ > c4) { tmp_ = c4; c4 = k_; k_ = tmp_; }                      \
        if (k_ > c5) { tmp_ = c5; c5 = k_; k_ = tmp_; }                      \
        if (k_ > c6) { tmp_ = c6; c6 = k_; k_ = tmp_; }                      \
        c7 = (k_ > c7) ? k_ : c7;                                            \
    }                                                                        \
} while (0)

__global__ __launch_bounds__(256, 8)
void rc_kernel(const int*   __restrict__ tgt_index,
               const float* __restrict__ knn_dists,
               const float* __restrict__ knn_key,
               const float* __restrict__ net_probs,
               const float* __restrict__ net_sel,
               const float* __restrict__ W_func, const float* __restrict__ b_func,
               const float* __restrict__ W1a,    const float* __restrict__ b1a,
               const float* __restrict__ W1b,    const float* __restrict__ b1b,
               const float* __restrict__ W2a,    const float* __restrict__ b2a,
               const float* __restrict__ W2b,    const float* __restrict__ b2b,
               float* __restrict__ out)
{
    const int t   = blockIdx.x;
    const int tid = threadIdx.x;

    __shared__ float s_cand[256 * 8];   // per-thread top-8 values
    __shared__ int   s_tgt[KNN];
    __shared__ float s_dist[KNN];
    __shared__ float s_cnt[KNN];
    __shared__ float s_top8[8];

    // ---- per-k loads (lanes 0..31) ----
    int   tg = 0;
    float d = 0.f, lk = 0.f, ls = 0.f;
    if (tid < KNN) {
        tg = tgt_index[t * KNN + tid];
        d  = knn_dists[t * KNN + tid];
        lk = logf(knn_key[t * KNN + tid]);
        ls = logf(net_sel[t * KNN + tid]);
        s_tgt[tid]  = tg;
        s_dist[tid] = d;
    }

    // ---- Phase 1: fused read (top-8 values scan) + zero-store of output row ----
    float t0 = 0.f, t1 = 0.f, t2 = 0.f, t3 = 0.f,
          t4 = 0.f, t5 = 0.f, t6 = 0.f, t7 = 0.f;
    const f4* np4 = (const f4*)(net_probs + (size_t)t * VOCAB);
    f4*       o4  = (f4*)(out + (size_t)t * VOCAB);
    const f4  z4  = (f4){0.f, 0.f, 0.f, 0.f};
    // 8000 float4s per row: 31 uniform iterations + tail for tid<64
    #pragma unroll 2
    for (int k = 0; k < 31; ++k) {
        PROC(tid + (k << 8));
    }
    if (tid < 64) {
        PROC(tid + (31 << 8));
    }

    // dump per-thread top-8 values
    s_cand[tid * 8 + 0] = t0;  s_cand[tid * 8 + 1] = t1;
    s_cand[tid * 8 + 2] = t2;  s_cand[tid * 8 + 3] = t3;
    s_cand[tid * 8 + 4] = t4;  s_cand[tid * 8 + 5] = t5;
    s_cand[tid * 8 + 6] = t6;  s_cand[tid * 8 + 7] = t7;
    __syncthreads();

    // ---- Phase 2: one wave merges 2048 candidates -> global top-8 values ----
    if (tid < 64) {
        ull c0 = 0, c1 = 0, c2 = 0, c3 = 0, c4 = 0, c5 = 0, c6 = 0, c7 = 0;
        for (int k = 0; k < 32; ++k) {
            int idx = tid + (k << 6);
            ull key = (((ull)__float_as_uint(s_cand[idx])) << 32) | (unsigned)idx;
            INSK(key);
        }
        for (int r = 0; r < 8; ++r) {
            ull g = c0;
            #pragma unroll
            for (int off = 1; off < 64; off <<= 1) {
                ull o = __shfl_xor(g, off);
                if (o > g) g = o;
            }
            if (c0 == g) {   // unique key -> exactly one lane pops
                c0 = c1; c1 = c2; c2 = c3; c3 = c4; c4 = c5; c5 = c6; c6 = c7; c7 = 0;
            }
            if (tid == 0) s_top8[r] = __uint_as_float((unsigned)(g >> 32));
        }
    }
    __syncthreads();

    // ---- Phase 3a: label counts (distinct, reference never counts label 0) ----
    if (tid < KNN) {
        int fo = (tg != 0) ? 1 : 0;
        if (fo) {
            for (int j = 0; j < tid; ++j)
                if (s_tgt[j] == tg) { fo = 0; break; }
        }
        int c = fo;
        #pragma unroll
        for (int off = 1; off < KNN; off <<= 1) {
            int n = __shfl_up(c, off, KNN);
            if (tid >= off) c += n;
        }
        s_cnt[tid] = (float)c;
    }
    __syncthreads();

    // ---- Phase 3b: tiny MLPs, softmaxes, scatter ----
    if (tid < KNN) {
        // noise_logit: Linear(2,4) -> tanh -> Linear(4,1)
        float noise = b1b[0];
        #pragma unroll
        for (int j = 0; j < 4; ++j) {
            float z = tanhf(W1a[2 * j] * lk + W1a[2 * j + 1] * ls + b1a[j]);
            noise += W1b[j] * z;
        }

        // sim_lambda = W_func . [log(top8) | log_key | log_sel] + b_func
        float sp = W_func[8 + tid] * lk + W_func[40 + tid] * ls;
        if (tid < 8) sp += W_func[tid] * logf(s_top8[tid]);
        #pragma unroll
        for (int off = 16; off; off >>= 1) sp += __shfl_xor(sp, off, KNN);
        float sim = sp + b_func[0];

        // lambda_logit: Linear(64,32) -> tanh -> Linear(32,2); lane = hidden unit
        float h = b2a[tid];
        const float* wr = W2a + tid * 64;
        #pragma unroll 8
        for (int i = 0; i < KNN; ++i) h += wr[i] * s_dist[i];
        #pragma unroll 8
        for (int i = 0; i < KNN; ++i) h += wr[KNN + i] * s_cnt[i];
        h = tanhf(h);
        float p0 = W2b[tid] * h;
        float p1 = W2b[KNN + tid] * h;
        #pragma unroll
        for (int off = 16; off; off >>= 1) {
            p0 += __shfl_xor(p0, off, KNN);
            p1 += __shfl_xor(p1, off, KNN);
        }
        float l0 = p0 + b2b[0];
        float l1 = p1 + b2b[1];

        float tempe = 1.f / (1.f + expf(-l1));          // sigmoid(l1)
        float lam   = 1.f / (1.f + expf(-(l0 - sim)));  // softmax([l0,sim])[0]

        // probs = softmax(-d*tempe + noise) over K
        float logit = -d * tempe + noise;
        float mx = logit;
        #pragma unroll
        for (int off = 16; off; off >>= 1) mx = fmaxf(mx, __shfl_xor(mx, off, KNN));
        float e = expf(logit - mx);
        float se = e;
        #pragma unroll
        for (int off = 16; off; off >>= 1) se += __shfl_xor(se, off, KNN);
        float p = e / se;

        // scatter, last-occurrence-wins on duplicate indices (numpy semantics)
        bool wrte = true;
        for (int j = tid + 1; j < KNN; ++j)
            if (s_tgt[j] == tg) { wrte = false; break; }
        if (wrte) out[(size_t)t * VOCAB + tg] = p;

        if (tid == 0) out[(size_t)TOKENS * VOCAB + t] = lam;
    }
}

extern "C" void kernel_launch(void* const* d_in, const int* in_sizes, int n_in,
                              void* d_out, int out_size, void* d_ws, size_t ws_size,
                              hipStream_t stream) {
    rc_kernel<<<TOKENS, 256, 0, stream>>>(
        (const int*)  d_in[0],   // tgt_index
        (const float*)d_in[1],   // knn_dists
        (const float*)d_in[2],   // knn_key_feature
        (const float*)d_in[3],   // network_probs
        (const float*)d_in[4],   // network_select_probs
        (const float*)d_in[5],  (const float*)d_in[6],   // W_func, b_func
        (const float*)d_in[7],  (const float*)d_in[8],   // W1a, b1a
        (const float*)d_in[9],  (const float*)d_in[10],  // W1b, b1b
        (const float*)d_in[11], (const float*)d_in[12],  // W2a, b2a
        (const float*)d_in[13], (const float*)d_in[14],  // W2b, b2b
        (float*)d_out);
}

// Round 7
// 128.726 us; speedup vs baseline: 1.7407x; 1.0749x over previous
//
#include <hip/hip_runtime.h>

typedef unsigned long long ull;
typedef float f4 __attribute__((ext_vector_type(4)));

#define TOKENS 2048
#define KNN    32
#define VOCAB  32000

// branch-free sorted-descending 8-float insert (values only), guarded
#define INSF(vv) do {                                                        \
    float x_ = (vv);                                                         \
    if (x_ > t7) {                                                           \
        float h_;                                                            \
        h_ = fmaxf(t0, x_); x_ = fminf(t0, x_); t0 = h_;                     \
        h_ = fmaxf(t1, x_); x_ = fminf(t1, x_); t1 = h_;                     \
        h_ = fmaxf(t2, x_); x_ = fminf(t2, x_); t2 = h_;                     \
        h_ = fmaxf(t3, x_); x_ = fminf(t3, x_); t3 = h_;                     \
        h_ = fmaxf(t4, x_); x_ = fminf(t4, x_); t4 = h_;                     \
        h_ = fmaxf(t5, x_); x_ = fminf(t5, x_); t5 = h_;                     \
        h_ = fmaxf(t6, x_); x_ = fminf(t6, x_); t6 = h_;                     \
        t7 = fmaxf(t7, x_);                                                  \
    }                                                                        \
} while (0)

#define PROCV(v_) do {                                                       \
    float m_ = fmaxf(fmaxf(v_.x, v_.y), fmaxf(v_.z, v_.w));                  \
    if (m_ > t7) { INSF(v_.x); INSF(v_.y); INSF(v_.z); INSF(v_.w); }         \
} while (0)

// u64 sorted insert for the (cold) phase-2 merge
#define INSK(key) do {                                                       \
    ull k_ = (key);                                                          \
    if (k_ > c7) {                                                           \
        ull tmp_;                                                            \
        if (k_ > c0) { tmp_ = c0; c0 = k_; k_ = tmp_; }                      \
        if (k_ > c1) { tmp_ = c1; c1 = k_; k_ = tmp_; }                      \
        if (k_ > c2) { tmp_ = c2; c2 = k_; k_ = tmp_; }                      \
        if (k_ > c3) { tmp_ = c3; c3 = k_; k_ = tmp_; }                      \
        if (k_ > c4) { tmp_ = c4; c4 = k_; k_ = tmp_; }                      \
        if (k_ > c5) { tmp_ = c5; c5 = k_; k_ = tmp_; }                      \
        if (k_ > c6) { tmp_ = c6; c6 = k_; k_ = tmp_; }                      \
        c7 = (k_ > c7) ? k_ : c7;                                            \
    }                                                                        \
} while (0)

__global__ __launch_bounds__(256, 8)
void rc_kernel(const int*   __restrict__ tgt_index,
               const float* __restrict__ knn_dists,
               const float* __restrict__ knn_key,
               const float* __restrict__ net_probs,
               const float* __restrict__ net_sel,
               const float* __restrict__ W_func, const float* __restrict__ b_func,
               const float* __restrict__ W1a,    const float* __restrict__ b1a,
               const float* __restrict__ W1b,    const float* __restrict__ b1b,
               const float* __restrict__ W2a,    const float* __restrict__ b2a,
               const float* __restrict__ W2b,    const float* __restrict__ b2b,
               float* __restrict__ out)
{
    const int t   = blockIdx.x;
    const int tid = threadIdx.x;

    __shared__ float s_cand[256 * 8];   // per-thread top-8 values
    __shared__ int   s_tgt[KNN];
    __shared__ float s_dist[KNN];
    __shared__ float s_cnt[KNN];
    __shared__ float s_top8[8];

    // ---- per-k loads (lanes 0..31) ----
    int   tg = 0;
    float d = 0.f, lk = 0.f, ls = 0.f;
    if (tid < KNN) {
        tg = tgt_index[t * KNN + tid];
        d  = knn_dists[t * KNN + tid];
        lk = logf(knn_key[t * KNN + tid]);
        ls = logf(net_sel[t * KNN + tid]);
        s_tgt[tid]  = tg;
        s_dist[tid] = d;
    }

    // ---- Phase 1: software-pipelined scan + fused zero-store ----
    // 8000 f4/row: k = 0..30 all 256 threads, k = 31 only tid < 64.
    // 31 = 7 groups of 4 + remainder of 3.
    float t0 = 0.f, t1 = 0.f, t2 = 0.f, t3 = 0.f,
          t4 = 0.f, t5 = 0.f, t6 = 0.f, t7 = 0.f;
    const f4* np4 = (const f4*)(net_probs + (size_t)t * VOCAB);
    f4*       o4  = (f4*)(out + (size_t)t * VOCAB);
    const f4  z4  = (f4){0.f, 0.f, 0.f, 0.f};

    f4 a0, a1, a2, a3, b0, b1, b2, b3;
    a0 = np4[tid + 0 * 256];
    a1 = np4[tid + 1 * 256];
    a2 = np4[tid + 2 * 256];
    a3 = np4[tid + 3 * 256];
    #pragma unroll
    for (int g = 0; g < 7; ++g) {
        const int kb = 4 * g;
        if (g < 6) {                      // prefetch next full group
            b0 = np4[tid + (kb + 4) * 256];
            b1 = np4[tid + (kb + 5) * 256];
            b2 = np4[tid + (kb + 6) * 256];
            b3 = np4[tid + (kb + 7) * 256];
        } else {                          // last prefetch: remainder k=28..30
            b0 = np4[tid + 28 * 256];
            b1 = np4[tid + 29 * 256];
            b2 = np4[tid + 30 * 256];
        }
        o4[tid + (kb + 0) * 256] = z4;
        o4[tid + (kb + 1) * 256] = z4;
        o4[tid + (kb + 2) * 256] = z4;
        o4[tid + (kb + 3) * 256] = z4;
        PROCV(a0); PROCV(a1); PROCV(a2); PROCV(a3);
        a0 = b0; a1 = b1; a2 = b2; a3 = b3;
    }
    // remainder k = 28..30 (already loaded in a0..a2)
    o4[tid + 28 * 256] = z4;
    o4[tid + 29 * 256] = z4;
    o4[tid + 30 * 256] = z4;
    PROCV(a0); PROCV(a1); PROCV(a2);
    if (tid < 64) {                       // tail k = 31
        f4 v = np4[tid + 31 * 256];
        o4[tid + 31 * 256] = z4;
        PROCV(v);
    }

    // dump per-thread top-8 values
    s_cand[tid * 8 + 0] = t0;  s_cand[tid * 8 + 1] = t1;
    s_cand[tid * 8 + 2] = t2;  s_cand[tid * 8 + 3] = t3;
    s_cand[tid * 8 + 4] = t4;  s_cand[tid * 8 + 5] = t5;
    s_cand[tid * 8 + 6] = t6;  s_cand[tid * 8 + 7] = t7;
    __syncthreads();

    // ---- Phase 2: one wave merges 2048 candidates -> global top-8 values ----
    if (tid < 64) {
        ull c0 = 0, c1 = 0, c2 = 0, c3 = 0, c4 = 0, c5 = 0, c6 = 0, c7 = 0;
        for (int k = 0; k < 32; ++k) {
            int idx = tid + (k << 6);
            ull key = (((ull)__float_as_uint(s_cand[idx])) << 32) | (unsigned)idx;
            INSK(key);
        }
        for (int r = 0; r < 8; ++r) {
            ull g = c0;
            #pragma unroll
            for (int off = 1; off < 64; off <<= 1) {
                ull o = __shfl_xor(g, off);
                if (o > g) g = o;
            }
            if (c0 == g) {   // unique key -> exactly one lane pops
                c0 = c1; c1 = c2; c2 = c3; c3 = c4; c4 = c5; c5 = c6; c6 = c7; c7 = 0;
            }
            if (tid == 0) s_top8[r] = __uint_as_float((unsigned)(g >> 32));
        }
    }
    __syncthreads();

    // ---- Phase 3a: label counts (distinct, reference never counts label 0) ----
    if (tid < KNN) {
        int fo = (tg != 0) ? 1 : 0;
        if (fo) {
            for (int j = 0; j < tid; ++j)
                if (s_tgt[j] == tg) { fo = 0; break; }
        }
        int c = fo;
        #pragma unroll
        for (int off = 1; off < KNN; off <<= 1) {
            int n = __shfl_up(c, off, KNN);
            if (tid >= off) c += n;
        }
        s_cnt[tid] = (float)c;
    }
    __syncthreads();

    // ---- Phase 3b: tiny MLPs, softmaxes, scatter ----
    if (tid < KNN) {
        // noise_logit: Linear(2,4) -> tanh -> Linear(4,1)
        float noise = b1b[0];
        #pragma unroll
        for (int j = 0; j < 4; ++j) {
            float z = tanhf(W1a[2 * j] * lk + W1a[2 * j + 1] * ls + b1a[j]);
            noise += W1b[j] * z;
        }

        // sim_lambda = W_func . [log(top8) | log_key | log_sel] + b_func
        float sp = W_func[8 + tid] * lk + W_func[40 + tid] * ls;
        if (tid < 8) sp += W_func[tid] * logf(s_top8[tid]);
        #pragma unroll
        for (int off = 16; off; off >>= 1) sp += __shfl_xor(sp, off, KNN);
        float sim = sp + b_func[0];

        // lambda_logit: Linear(64,32) -> tanh -> Linear(32,2); lane = hidden unit
        float h = b2a[tid];
        const float* wr = W2a + tid * 64;
        #pragma unroll 8
        for (int i = 0; i < KNN; ++i) h += wr[i] * s_dist[i];
        #pragma unroll 8
        for (int i = 0; i < KNN; ++i) h += wr[KNN + i] * s_cnt[i];
        h = tanhf(h);
        float p0 = W2b[tid] * h;
        float p1 = W2b[KNN + tid] * h;
        #pragma unroll
        for (int off = 16; off; off >>= 1) {
            p0 += __shfl_xor(p0, off, KNN);
            p1 += __shfl_xor(p1, off, KNN);
        }
        float l0 = p0 + b2b[0];
        float l1 = p1 + b2b[1];

        float tempe = 1.f / (1.f + expf(-l1));          // sigmoid(l1)
        float lam   = 1.f / (1.f + expf(-(l0 - sim)));  // softmax([l0,sim])[0]

        // probs = softmax(-d*tempe + noise) over K
        float logit = -d * tempe + noise;
        float mx = logit;
        #pragma unroll
        for (int off = 16; off; off >>= 1) mx = fmaxf(mx, __shfl_xor(mx, off, KNN));
        float e = expf(logit - mx);
        float se = e;
        #pragma unroll
        for (int off = 16; off; off >>= 1) se += __shfl_xor(se, off, KNN);
        float p = e / se;

        // scatter, last-occurrence-wins on duplicate indices (numpy semantics)
        bool wrte = true;
        for (int j = tid + 1; j < KNN; ++j)
            if (s_tgt[j] == tg) { wrte = false; break; }
        if (wrte) out[(size_t)t * VOCAB + tg] = p;

        if (tid == 0) out[(size_t)TOKENS * VOCAB + t] = lam;
    }
}

extern "C" void kernel_launch(void* const* d_in, const int* in_sizes, int n_in,
                              void* d_out, int out_size, void* d_ws, size_t ws_size,
                              hipStream_t stream) {
    rc_kernel<<<TOKENS, 256, 0, stream>>>(
        (const int*)  d_in[0],   // tgt_index
        (const float*)d_in[1],   // knn_dists
        (const float*)d_in[2],   // knn_key_feature
        (const float*)d_in[3],   // network_probs
        (const float*)d_in[4],   // network_select_probs
        (const float*)d_in[5],  (const float*)d_in[6],   // W_func, b_func
        (const float*)d_in[7],  (const float*)d_in[8],   // W1a, b1a
        (const float*)d_in[9],  (const float*)d_in[10],  // W1b, b1b
        (const float*)d_in[11], (const float*)d_in[12],  // W2a, b2a
        (const float*)d_in[13], (const float*)d_in[14],  // W2b, b2b
        (float*)d_out);
}